// Round 4
// baseline (254.537 us; speedup 1.0000x reference)
//
#include <hip/hip_runtime.h>
#include <math.h>

typedef unsigned short ushort_t;
typedef __attribute__((ext_vector_type(8))) short bf16x8;
typedef __attribute__((ext_vector_type(4))) float f32x4;
typedef __attribute__((ext_vector_type(8))) unsigned short u16x8;

#define N_TOK 65536
#define DIN 128
#define HD 256
#define DOUT 128
#define NEXP 8
#define MT 64
#define MAX_TILES (N_TOK / MT) /* 1024 */

__device__ __forceinline__ unsigned short f2bf(float f) {
    union { float f; unsigned int i; } v; v.f = f;
    unsigned int i = v.i;
    return (unsigned short)((i + 0x7FFFu + ((i >> 16) & 1u)) >> 16); // RNE
}

// ---------------------------------------------------------------------------
// Pack fp32 W1/W2/Wo into bf16 MFMA B-fragment order:
// chunk index (per expert) = (ntile*KSTEPS + kstep)*64 + lane, lane=q*16+m,
// chunk content j=0..7 = W[k = kstep*32 + q*8 + j][n = ntile*16 + m].
// ---------------------------------------------------------------------------
__global__ void pack_weights(const float* __restrict__ W1,
                             const float* __restrict__ W2,
                             const float* __restrict__ Wo,
                             ushort_t* __restrict__ wt1f,
                             ushort_t* __restrict__ wt2f,
                             ushort_t* __restrict__ wotf) {
    int id = blockIdx.x * 256 + threadIdx.x;
    const float* src; ushort_t* dst; int Nn, ksteps, c;
    if (id < 32768) {            // W1
        int e = id >> 12; c = id & 4095;
        Nn = HD; ksteps = 4; src = W1 + (size_t)e * DIN * HD; dst = wt1f + (size_t)id * 8;
    } else if (id < 98304) {     // W2
        int t = id - 32768; int e = t >> 13; c = t & 8191;
        Nn = HD; ksteps = 8; src = W2 + (size_t)e * HD * HD; dst = wt2f + (size_t)t * 8;
    } else {                     // Wo
        int t = id - 98304; c = t;
        Nn = DOUT; ksteps = 8; src = Wo; dst = wotf + (size_t)t * 8;
    }
    int L = c & 63; int kc = c >> 6;
    int kstep = kc % ksteps; int ntile = kc / ksteps;
    int q = L >> 4, m = L & 15;
    int n = ntile * 16 + m; int k0 = kstep * 32 + q * 8;
    u16x8 v;
#pragma unroll
    for (int j = 0; j < 8; j++) v[j] = f2bf(src[(size_t)(k0 + j) * Nn + n]);
    *(u16x8*)dst = v;
}

// ---------------------------------------------------------------------------
// Router v4, K-split: lane = (token_local*8 + kslice). Each thread loads 64B
// of x (wave covers 4KB contiguous -> perfectly coalesced, x read exactly
// once), computes 8 partial logits (16 FMA each) vs transposed+padded Wg in
// LDS, then a 3-round shfl_xor butterfly over the 8 kslices gives every lane
// all 8 exact fp32 logits. In-thread top-2 + softmax; two-phase LDS counting
// for list insertion (8 global atomics per block).
// ---------------------------------------------------------------------------
#define RT_TPB 32   /* tokens per 256-thread block */
__global__ __launch_bounds__(256)
void router_kernel(const float* __restrict__ x,
                   const float* __restrict__ Wg,
                   int* __restrict__ counts,
                   int* __restrict__ list_tok,
                   float* __restrict__ list_w) {
    __shared__ float wgsT[NEXP * 132]; // [e][k], padded: conflict-light b128
    __shared__ int lcnt[NEXP];
    __shared__ int lbase[NEXP];
    int tid = threadIdx.x;
    if (tid < NEXP) lcnt[tid] = 0;
    for (int i = tid; i < DIN * NEXP; i += 256) {
        int e = i & 7, k = i >> 3;   // Wg[k][e]
        wgsT[e * 132 + k] = Wg[i];
    }
    __syncthreads();

    int s = tid & 7;          // kslice 0..7 (16 K-elems each)
    int tl = tid >> 3;        // token 0..31 within block
    int n = blockIdx.x * RT_TPB + tl;

    const float4* xr = (const float4*)(x + (size_t)n * DIN + s * 16);
    float4 xv[4];
#pragma unroll
    for (int j = 0; j < 4; j++) xv[j] = xr[j];

    float lg[NEXP];
#pragma unroll
    for (int e = 0; e < NEXP; e++) {
        const float4* wp = (const float4*)(wgsT + e * 132 + s * 16);
        float a = 0.f;
#pragma unroll
        for (int j = 0; j < 4; j++) {
            float4 wv = wp[j];
            a += xv[j].x * wv.x + xv[j].y * wv.y + xv[j].z * wv.z + xv[j].w * wv.w;
        }
        lg[e] = a;
    }
    // butterfly-sum over the 8 kslices (lanes differing in low 3 bits)
#pragma unroll
    for (int d = 1; d < 8; d <<= 1) {
#pragma unroll
        for (int e = 0; e < NEXP; e++) lg[e] += __shfl_xor(lg[e], d, 64);
    }
    // in-thread top-2 (ties -> lowest index, matching lax.top_k)
    int e0 = 0; float v0 = lg[0];
#pragma unroll
    for (int e = 1; e < NEXP; e++) if (lg[e] > v0) { v0 = lg[e]; e0 = e; }
    int e1 = -1; float v1 = -3.0e38f;
#pragma unroll
    for (int e = 0; e < NEXP; e++) if (e != e0 && lg[e] > v1) { v1 = lg[e]; e1 = e; }
    float t = expf(v1 - v0);
    float inv = 1.0f / (1.0f + t);
    float w0 = inv, w1 = t * inv;

    bool writer = (s == 0);
    int p0 = 0, p1 = 0;
    if (writer) {
        p0 = atomicAdd(&lcnt[e0], 1);
        p1 = atomicAdd(&lcnt[e1], 1);
    }
    __syncthreads();
    if (tid < NEXP) lbase[tid] = atomicAdd(&counts[tid], lcnt[tid]);
    __syncthreads();
    if (writer) {
        int q0 = lbase[e0] + p0;
        list_tok[e0 * N_TOK + q0] = n;
        list_w[e0 * N_TOK + q0] = w0;
        int q1 = lbase[e1] + p1;
        list_tok[e1 * N_TOK + q1] = n;
        list_w[e1 * N_TOK + q1] = w1;
    }
}

// ---------------------------------------------------------------------------
// init d_out with broadcast bo (softmax weights sum to 1, bo added once).
// ---------------------------------------------------------------------------
__global__ void init_out(const float* __restrict__ bo, float* __restrict__ out) {
    int gid = blockIdx.x * 256 + threadIdx.x; // N*DOUT/4 float4 groups
    float4 b = ((const float4*)bo)[gid & 31];
    ((float4*)out)[gid] = b;
}

// ---------------------------------------------------------------------------
// Fused per-expert MLP, 64-token tiles, 2m x 2n wave split:
// wave w: mw = w>>1 owns mtiles {2mw, 2mw+1} (32 tokens), nw = w&1 owns the
// nw-half of N. Halves per-wave LDS A-frag reads vs the 1m x 4n split
// (block LDS traffic 400KB -> 240KB) at the cost of 2x weight reads from L2
// (L2 has ~5x headroom at 7 TB/s observed).
// LDS: bufA 16KB (x), bufH 32KB (h1 then h2) -> 48.5KB, 3 blocks/CU.
// ---------------------------------------------------------------------------
__global__ __launch_bounds__(256, 3)
void expert_kernel(const float* __restrict__ x,
                   const int* __restrict__ counts,
                   const int* __restrict__ list_tok,
                   const float* __restrict__ list_w,
                   const ushort_t* __restrict__ wt1f,
                   const ushort_t* __restrict__ wt2f,
                   const ushort_t* __restrict__ wotf,
                   const float* __restrict__ b1,
                   const float* __restrict__ b2,
                   float* __restrict__ out) {
    int e = blockIdx.x & 7;
    int tile = blockIdx.x >> 3;
    int cnt = counts[e];
    int base = tile * MT;
    if (base >= cnt) return;
    int rows = cnt - base; if (rows > MT) rows = MT;

    __shared__ __align__(16) ushort_t bufA[8192];  // 16KB: x tile
    __shared__ __align__(16) ushort_t bufH[16384]; // 32KB: h1, then h2
    __shared__ int toks_s[MT];
    __shared__ float wts_s[MT];

    int tid = threadIdx.x;
    int lane = tid & 63;
    int w = tid >> 6;
    int mw = w >> 1;   // 0,1: owns mtiles 2mw, 2mw+1
    int nw = w & 1;    // 0,1: owns N-half
    int q = lane >> 4;
    int mcol = lane & 15;

    if (tid < MT) {
        int rr = tid < rows ? tid : rows - 1;
        toks_s[tid] = list_tok[(size_t)e * N_TOK + base + rr];
        wts_s[tid] = list_w[(size_t)e * N_TOK + base + rr];
    }
    // stage x tile (fp32 -> bf16) into A-frag layout (1024 16B chunks)
    for (int c = tid; c < 1024; c += 256) {
        int row = c >> 4;
        int kchunk = c & 15;
        int rr = row < rows ? row : rows - 1;
        int tok = list_tok[(size_t)e * N_TOK + base + rr];
        const float4* src = (const float4*)(x + (size_t)tok * DIN + kchunk * 8);
        float4 lo = src[0], hi = src[1];
        u16x8 v;
        v[0] = f2bf(lo.x); v[1] = f2bf(lo.y); v[2] = f2bf(lo.z); v[3] = f2bf(lo.w);
        v[4] = f2bf(hi.x); v[5] = f2bf(hi.y); v[6] = f2bf(hi.z); v[7] = f2bf(hi.w);
        int kstep = kchunk >> 2, qq = kchunk & 3;
        int dchunk = (kstep * 4 + (row >> 4)) * 64 + qq * 16 + (row & 15);
        ((u16x8*)bufA)[dchunk] = v;
    }
    __syncthreads();

    const bf16x8* Albs = (const bf16x8*)bufA;
    const bf16x8* Hlbs = (const bf16x8*)bufH;

    // ---- GEMM1: x[64x128] @ W1[128x256] -> h1 ----
    f32x4 acc[2][8];
#pragma unroll
    for (int mtl = 0; mtl < 2; mtl++)
#pragma unroll
        for (int nt = 0; nt < 8; nt++) acc[mtl][nt] = (f32x4){0.f, 0.f, 0.f, 0.f};
    const bf16x8* B1 = (const bf16x8*)(wt1f + (size_t)e * 4096 * 8);
#pragma unroll
    for (int kstep = 0; kstep < 4; kstep++) {
        bf16x8 a[2];
#pragma unroll
        for (int mtl = 0; mtl < 2; mtl++)
            a[mtl] = Albs[(kstep * 4 + mw * 2 + mtl) * 64 + lane];
#pragma unroll
        for (int nt = 0; nt < 8; nt++) {
            bf16x8 b = B1[((nw * 8 + nt) * 4 + kstep) * 64 + lane];
#pragma unroll
            for (int mtl = 0; mtl < 2; mtl++)
                acc[mtl][nt] = __builtin_amdgcn_mfma_f32_16x16x32_bf16(a[mtl], b, acc[mtl][nt], 0, 0, 0);
        }
    }
    // epilogue 1: bias + relu -> bufH (h1) in A-frag layout
#pragma unroll
    for (int nt = 0; nt < 8; nt++) {
        int nn = nw * 128 + nt * 16 + mcol;
        float bias = b1[e * HD + nn];
        int kstep = nn >> 5, qq = (nn >> 3) & 3, jj = nn & 7;
#pragma unroll
        for (int mtl = 0; mtl < 2; mtl++) {
            int mt = mw * 2 + mtl;
#pragma unroll
            for (int r = 0; r < 4; r++) {
                float v = acc[mtl][nt][r] + bias;
                v = v > 0.f ? v : 0.f;
                int chunk = (kstep * 4 + mt) * 64 + qq * 16 + q * 4 + r;
                bufH[chunk * 8 + jj] = f2bf(v);
            }
        }
    }
    __syncthreads();

    // ---- GEMM2: h1[64x256] @ W2[256x256] -> h2 (regs) ----
    f32x4 acc2[2][8];
#pragma unroll
    for (int mtl = 0; mtl < 2; mtl++)
#pragma unroll
        for (int nt = 0; nt < 8; nt++) acc2[mtl][nt] = (f32x4){0.f, 0.f, 0.f, 0.f};
    const bf16x8* B2 = (const bf16x8*)(wt2f + (size_t)e * 8192 * 8);
#pragma unroll
    for (int kstep = 0; kstep < 8; kstep++) {
        bf16x8 a[2];
#pragma unroll
        for (int mtl = 0; mtl < 2; mtl++)
            a[mtl] = Hlbs[(kstep * 4 + mw * 2 + mtl) * 64 + lane];
#pragma unroll
        for (int nt = 0; nt < 8; nt++) {
            bf16x8 b = B2[((nw * 8 + nt) * 8 + kstep) * 64 + lane];
#pragma unroll
            for (int mtl = 0; mtl < 2; mtl++)
                acc2[mtl][nt] = __builtin_amdgcn_mfma_f32_16x16x32_bf16(a[mtl], b, acc2[mtl][nt], 0, 0, 0);
        }
    }
    __syncthreads();  // all waves done READING h1 before we overwrite bufH
    // epilogue 2: bias + relu -> bufH (h2 over h1; h1 is dead)
#pragma unroll
    for (int nt = 0; nt < 8; nt++) {
        int nn = nw * 128 + nt * 16 + mcol;
        float bias = b2[e * HD + nn];
        int kstep = nn >> 5, qq = (nn >> 3) & 3, jj = nn & 7;
#pragma unroll
        for (int mtl = 0; mtl < 2; mtl++) {
            int mt = mw * 2 + mtl;
#pragma unroll
            for (int r = 0; r < 4; r++) {
                float v = acc2[mtl][nt][r] + bias;
                v = v > 0.f ? v : 0.f;
                int chunk = (kstep * 4 + mt) * 64 + qq * 16 + q * 4 + r;
                bufH[chunk * 8 + jj] = f2bf(v);
            }
        }
    }
    __syncthreads();

    // ---- GEMM3: h2[64x256] @ Wo[256x128] -> y; weighted atomic combine ----
    f32x4 acc3[2][4];
#pragma unroll
    for (int mtl = 0; mtl < 2; mtl++)
#pragma unroll
        for (int nt = 0; nt < 4; nt++) acc3[mtl][nt] = (f32x4){0.f, 0.f, 0.f, 0.f};
    const bf16x8* B3 = (const bf16x8*)wotf;
#pragma unroll
    for (int kstep = 0; kstep < 8; kstep++) {
        bf16x8 a[2];
#pragma unroll
        for (int mtl = 0; mtl < 2; mtl++)
            a[mtl] = Hlbs[(kstep * 4 + mw * 2 + mtl) * 64 + lane];
#pragma unroll
        for (int nt = 0; nt < 4; nt++) {
            bf16x8 b = B3[((nw * 4 + nt) * 8 + kstep) * 64 + lane];
#pragma unroll
            for (int mtl = 0; mtl < 2; mtl++)
                acc3[mtl][nt] = __builtin_amdgcn_mfma_f32_16x16x32_bf16(a[mtl], b, acc3[mtl][nt], 0, 0, 0);
        }
    }
#pragma unroll
    for (int mtl = 0; mtl < 2; mtl++) {
        int mt = mw * 2 + mtl;
#pragma unroll
        for (int r = 0; r < 4; r++) {
            int row = mt * 16 + q * 4 + r;
            if (row < rows) {
                int tok = toks_s[row];
                float wgt = wts_s[row];
                float* dst = out + (size_t)tok * DOUT;
#pragma unroll
                for (int nt = 0; nt < 4; nt++) {
                    int col = (nw * 4 + nt) * 16 + mcol;
                    atomicAdd(&dst[col], wgt * acc3[mtl][nt][r]);
                }
            }
        }
    }
}

extern "C" void kernel_launch(void* const* d_in, const int* in_sizes, int n_in,
                              void* d_out, int out_size, void* d_ws, size_t ws_size,
                              hipStream_t stream) {
    const float* x  = (const float*)d_in[0];
    const float* Wg = (const float*)d_in[1];
    const float* W1 = (const float*)d_in[2];
    const float* b1 = (const float*)d_in[3];
    const float* W2 = (const float*)d_in[4];
    const float* b2 = (const float*)d_in[5];
    const float* Wo = (const float*)d_in[6];
    const float* bo = (const float*)d_in[7];
    float* out = (float*)d_out;

    char* ws = (char*)d_ws;
    size_t off = 0;
    int* counts    = (int*)(ws + off);    off += 256;
    int* list_tok  = (int*)(ws + off);    off += (size_t)NEXP * N_TOK * 4;
    float* list_w  = (float*)(ws + off);  off += (size_t)NEXP * N_TOK * 4;
    ushort_t* wt1f = (ushort_t*)(ws + off); off += (size_t)NEXP * DIN * HD * 2;
    ushort_t* wt2f = (ushort_t*)(ws + off); off += (size_t)NEXP * HD * HD * 2;
    ushort_t* wotf = (ushort_t*)(ws + off); off += (size_t)HD * DOUT * 2;

    hipMemsetAsync(counts, 0, 256, stream);
    pack_weights<<<400, 256, 0, stream>>>(W1, W2, Wo, wt1f, wt2f, wotf);
    router_kernel<<<N_TOK / RT_TPB, 256, 0, stream>>>(x, Wg, counts, list_tok, list_w);
    init_out<<<(N_TOK * DOUT / 4) / 256, 256, 0, stream>>>(bo, out);
    expert_kernel<<<NEXP * MAX_TILES, 256, 0, stream>>>(x, counts, list_tok, list_w,
                                                        wt1f, wt2f, wotf, b1, b2, out);
}

// Round 5
// 213.811 us; speedup vs baseline: 1.1905x; 1.1905x over previous
//
#include <hip/hip_runtime.h>
#include <math.h>

typedef unsigned short ushort_t;
typedef __attribute__((ext_vector_type(8))) short bf16x8;
typedef __attribute__((ext_vector_type(4))) float f32x4;
typedef __attribute__((ext_vector_type(8))) unsigned short u16x8;

#define N_TOK 65536
#define DIN 128
#define HD 256
#define DOUT 128
#define NEXP 8
#define MT 64
#define NSEG 32     /* segments per expert (atomic spreading) */
#define SEGCAP 2048 /* exact worst case: 64 blocks x 32 tokens share a segment */
#define SEGTILES (SEGCAP / MT) /* 32 */

__device__ __forceinline__ unsigned short f2bf(float f) {
    union { float f; unsigned int i; } v; v.f = f;
    unsigned int i = v.i;
    return (unsigned short)((i + 0x7FFFu + ((i >> 16) & 1u)) >> 16); // RNE
}

// ---------------------------------------------------------------------------
// Pack fp32 W1/W2/Wo into bf16 MFMA B-fragment order. Block 0 also zeroes the
// 8x32 segment counters (dispatch boundary orders this before router).
// chunk index (per expert) = (ntile*KSTEPS + kstep)*64 + lane, lane=q*16+m,
// chunk content j=0..7 = W[k = kstep*32 + q*8 + j][n = ntile*16 + m].
// ---------------------------------------------------------------------------
__global__ void pack_weights(const float* __restrict__ W1,
                             const float* __restrict__ W2,
                             const float* __restrict__ Wo,
                             ushort_t* __restrict__ wt1f,
                             ushort_t* __restrict__ wt2f,
                             ushort_t* __restrict__ wotf,
                             int* __restrict__ segcnt) {
    if (blockIdx.x == 0) segcnt[threadIdx.x] = 0; // 256 = NEXP*NSEG exactly
    int id = blockIdx.x * 256 + threadIdx.x;
    const float* src; ushort_t* dst; int Nn, ksteps, c;
    if (id < 32768) {            // W1
        int e = id >> 12; c = id & 4095;
        Nn = HD; ksteps = 4; src = W1 + (size_t)e * DIN * HD; dst = wt1f + (size_t)id * 8;
    } else if (id < 98304) {     // W2
        int t = id - 32768; int e = t >> 13; c = t & 8191;
        Nn = HD; ksteps = 8; src = W2 + (size_t)e * HD * HD; dst = wt2f + (size_t)t * 8;
    } else {                     // Wo
        int t = id - 98304; c = t;
        Nn = DOUT; ksteps = 8; src = Wo; dst = wotf + (size_t)t * 8;
    }
    int L = c & 63; int kc = c >> 6;
    int kstep = kc % ksteps; int ntile = kc / ksteps;
    int q = L >> 4, m = L & 15;
    int n = ntile * 16 + m; int k0 = kstep * 32 + q * 8;
    u16x8 v;
#pragma unroll
    for (int j = 0; j < 8; j++) v[j] = f2bf(src[(size_t)(k0 + j) * Nn + n]);
    *(u16x8*)dst = v;
}

// ---------------------------------------------------------------------------
// Router v5, K-split + segmented counters: lane = (token_local*8 + kslice).
// Each thread loads 64B of x (coalesced, x read once), 8 partial logits vs
// transposed Wg in LDS, 3-round shfl_xor butterfly -> all 8 exact fp32
// logits per lane; in-thread top-2 + softmax. Insertion: two-phase LDS
// counting, then 8 global atomics per block spread over NSEG=32 counter
// copies (c = blockIdx%32) -> 64 serialized atomics per counter instead of
// 2048 (the round-3/4 hidden ~90us bottleneck).
// ---------------------------------------------------------------------------
#define RT_TPB 32   /* tokens per 256-thread block */
__global__ __launch_bounds__(256)
void router_kernel(const float* __restrict__ x,
                   const float* __restrict__ Wg,
                   int* __restrict__ segcnt,
                   int* __restrict__ list_tok,
                   float* __restrict__ list_w) {
    __shared__ float wgsT[NEXP * 132]; // [e][k], padded
    __shared__ int lcnt[NEXP];
    __shared__ int lbase[NEXP];
    int tid = threadIdx.x;
    if (tid < NEXP) lcnt[tid] = 0;
    for (int i = tid; i < DIN * NEXP; i += 256) {
        int e = i & 7, k = i >> 3;   // Wg[k][e]
        wgsT[e * 132 + k] = Wg[i];
    }
    __syncthreads();

    int s = tid & 7;          // kslice 0..7 (16 K-elems each)
    int tl = tid >> 3;        // token 0..31 within block
    int n = blockIdx.x * RT_TPB + tl;

    const float4* xr = (const float4*)(x + (size_t)n * DIN + s * 16);
    float4 xv[4];
#pragma unroll
    for (int j = 0; j < 4; j++) xv[j] = xr[j];

    float lg[NEXP];
#pragma unroll
    for (int e = 0; e < NEXP; e++) {
        const float4* wp = (const float4*)(wgsT + e * 132 + s * 16);
        float a = 0.f;
#pragma unroll
        for (int j = 0; j < 4; j++) {
            float4 wv = wp[j];
            a += xv[j].x * wv.x + xv[j].y * wv.y + xv[j].z * wv.z + xv[j].w * wv.w;
        }
        lg[e] = a;
    }
#pragma unroll
    for (int d = 1; d < 8; d <<= 1) {
#pragma unroll
        for (int e = 0; e < NEXP; e++) lg[e] += __shfl_xor(lg[e], d, 64);
    }
    // in-thread top-2 (ties -> lowest index, matching lax.top_k)
    int e0 = 0; float v0 = lg[0];
#pragma unroll
    for (int e = 1; e < NEXP; e++) if (lg[e] > v0) { v0 = lg[e]; e0 = e; }
    int e1 = -1; float v1 = -3.0e38f;
#pragma unroll
    for (int e = 0; e < NEXP; e++) if (e != e0 && lg[e] > v1) { v1 = lg[e]; e1 = e; }
    float t = expf(v1 - v0);
    float inv = 1.0f / (1.0f + t);
    float w0 = inv, w1 = t * inv;

    bool writer = (s == 0);
    int p0 = 0, p1 = 0;
    if (writer) {
        p0 = atomicAdd(&lcnt[e0], 1);
        p1 = atomicAdd(&lcnt[e1], 1);
    }
    __syncthreads();
    int c = blockIdx.x & (NSEG - 1);
    if (tid < NEXP) lbase[tid] = atomicAdd(&segcnt[tid * NSEG + c], lcnt[tid]);
    __syncthreads();
    if (writer) {
        int q0 = lbase[e0] + p0;
        int idx0 = (e0 * NSEG + c) * SEGCAP + q0;
        list_tok[idx0] = n;
        list_w[idx0] = w0;
        int q1 = lbase[e1] + p1;
        int idx1 = (e1 * NSEG + c) * SEGCAP + q1;
        list_tok[idx1] = n;
        list_w[idx1] = w1;
    }
}

// ---------------------------------------------------------------------------
// init d_out with broadcast bo (softmax weights sum to 1, bo added once).
// ---------------------------------------------------------------------------
__global__ void init_out(const float* __restrict__ bo, float* __restrict__ out) {
    int gid = blockIdx.x * 256 + threadIdx.x; // N*DOUT/4 float4 groups
    float4 b = ((const float4*)bo)[gid & 31];
    ((float4*)out)[gid] = b;
}

// ---------------------------------------------------------------------------
// Fused per-expert MLP, 64-token tiles, 1m x 4n wave split (round-3 proven
// structure: wave w owns all 4 mtiles and N-quarter w; B-frags read once per
// block from L2). Block = (expert e, segment c, tile t within segment).
// LDS: bufA 16KB (x), bufH 32KB (h1 then h2 in place) -> 48.5KB, 3 blocks/CU.
// ---------------------------------------------------------------------------
__global__ __launch_bounds__(256, 3)
void expert_kernel(const float* __restrict__ x,
                   const int* __restrict__ segcnt,
                   const int* __restrict__ list_tok,
                   const float* __restrict__ list_w,
                   const ushort_t* __restrict__ wt1f,
                   const ushort_t* __restrict__ wt2f,
                   const ushort_t* __restrict__ wotf,
                   const float* __restrict__ b1,
                   const float* __restrict__ b2,
                   float* __restrict__ out) {
    int bid = blockIdx.x;
    int e = bid & 7;
    int c = (bid >> 3) & (NSEG - 1);
    int t = bid >> 8;            // 0..SEGTILES-1
    int cnt = segcnt[e * NSEG + c];
    int base = t * MT;
    if (base >= cnt) return;
    int rows = cnt - base; if (rows > MT) rows = MT;
    int lidx = (e * NSEG + c) * SEGCAP + base;

    __shared__ __align__(16) ushort_t bufA[8192];  // 16KB: x tile
    __shared__ __align__(16) ushort_t bufH[16384]; // 32KB: h1, then h2
    __shared__ int toks_s[MT];
    __shared__ float wts_s[MT];

    int tid = threadIdx.x;
    int lane = tid & 63;
    int w = tid >> 6;
    int q = lane >> 4;
    int mcol = lane & 15;

    if (tid < MT) {
        int rr = tid < rows ? tid : rows - 1;
        toks_s[tid] = list_tok[lidx + rr];
        wts_s[tid] = list_w[lidx + rr];
    }
    // stage x tile (fp32 -> bf16) into A-frag layout (1024 16B chunks)
    for (int cc = tid; cc < 1024; cc += 256) {
        int row = cc >> 4;
        int kchunk = cc & 15;
        int rr = row < rows ? row : rows - 1;
        int tok = list_tok[lidx + rr];
        const float4* src = (const float4*)(x + (size_t)tok * DIN + kchunk * 8);
        float4 lo = src[0], hi = src[1];
        u16x8 v;
        v[0] = f2bf(lo.x); v[1] = f2bf(lo.y); v[2] = f2bf(lo.z); v[3] = f2bf(lo.w);
        v[4] = f2bf(hi.x); v[5] = f2bf(hi.y); v[6] = f2bf(hi.z); v[7] = f2bf(hi.w);
        int kstep = kchunk >> 2, qq = kchunk & 3;
        int dchunk = (kstep * 4 + (row >> 4)) * 64 + qq * 16 + (row & 15);
        ((u16x8*)bufA)[dchunk] = v;
    }
    __syncthreads();

    const bf16x8* Albs = (const bf16x8*)bufA;
    const bf16x8* Hlbs = (const bf16x8*)bufH;

    // ---- GEMM1: x[64x128] @ W1[128x256] -> h1 ----
    f32x4 acc[4][4];
#pragma unroll
    for (int mt = 0; mt < 4; mt++)
#pragma unroll
        for (int nt = 0; nt < 4; nt++) acc[mt][nt] = (f32x4){0.f, 0.f, 0.f, 0.f};
    const bf16x8* B1 = (const bf16x8*)(wt1f + (size_t)e * 4096 * 8);
#pragma unroll
    for (int kstep = 0; kstep < 4; kstep++) {
        bf16x8 a[4];
#pragma unroll
        for (int mt = 0; mt < 4; mt++) a[mt] = Albs[(kstep * 4 + mt) * 64 + lane];
#pragma unroll
        for (int nt = 0; nt < 4; nt++) {
            bf16x8 b = B1[((w * 4 + nt) * 4 + kstep) * 64 + lane];
#pragma unroll
            for (int mt = 0; mt < 4; mt++)
                acc[mt][nt] = __builtin_amdgcn_mfma_f32_16x16x32_bf16(a[mt], b, acc[mt][nt], 0, 0, 0);
        }
    }
    // epilogue 1: bias + relu -> bufH (h1) in A-frag layout
#pragma unroll
    for (int nt = 0; nt < 4; nt++) {
        int nn = (w * 4 + nt) * 16 + mcol;
        float bias = b1[e * HD + nn];
        int kstep = nn >> 5, qq = (nn >> 3) & 3, jj = nn & 7;
#pragma unroll
        for (int mt = 0; mt < 4; mt++) {
#pragma unroll
            for (int r = 0; r < 4; r++) {
                float v = acc[mt][nt][r] + bias;
                v = v > 0.f ? v : 0.f;
                int chunk = (kstep * 4 + mt) * 64 + qq * 16 + q * 4 + r;
                bufH[chunk * 8 + jj] = f2bf(v);
            }
        }
    }
    __syncthreads();

    // ---- GEMM2: h1[64x256] @ W2[256x256] -> h2 (regs) ----
    f32x4 acc2[4][4];
#pragma unroll
    for (int mt = 0; mt < 4; mt++)
#pragma unroll
        for (int nt = 0; nt < 4; nt++) acc2[mt][nt] = (f32x4){0.f, 0.f, 0.f, 0.f};
    const bf16x8* B2 = (const bf16x8*)(wt2f + (size_t)e * 8192 * 8);
#pragma unroll
    for (int kstep = 0; kstep < 8; kstep++) {
        bf16x8 a[4];
#pragma unroll
        for (int mt = 0; mt < 4; mt++) a[mt] = Hlbs[(kstep * 4 + mt) * 64 + lane];
#pragma unroll
        for (int nt = 0; nt < 4; nt++) {
            bf16x8 b = B2[((w * 4 + nt) * 8 + kstep) * 64 + lane];
#pragma unroll
            for (int mt = 0; mt < 4; mt++)
                acc2[mt][nt] = __builtin_amdgcn_mfma_f32_16x16x32_bf16(a[mt], b, acc2[mt][nt], 0, 0, 0);
        }
    }
    __syncthreads();  // all waves done READING h1 before we overwrite bufH
    // epilogue 2: bias + relu -> bufH (h2 over h1; h1 is dead)
#pragma unroll
    for (int nt = 0; nt < 4; nt++) {
        int nn = (w * 4 + nt) * 16 + mcol;
        float bias = b2[e * HD + nn];
        int kstep = nn >> 5, qq = (nn >> 3) & 3, jj = nn & 7;
#pragma unroll
        for (int mt = 0; mt < 4; mt++) {
#pragma unroll
            for (int r = 0; r < 4; r++) {
                float v = acc2[mt][nt][r] + bias;
                v = v > 0.f ? v : 0.f;
                int chunk = (kstep * 4 + mt) * 64 + qq * 16 + q * 4 + r;
                bufH[chunk * 8 + jj] = f2bf(v);
            }
        }
    }
    __syncthreads();

    // ---- GEMM3: h2[64x256] @ Wo[256x128] -> y; weighted atomic combine ----
    f32x4 acc3[4][2];
#pragma unroll
    for (int mt = 0; mt < 4; mt++)
#pragma unroll
        for (int nt = 0; nt < 2; nt++) acc3[mt][nt] = (f32x4){0.f, 0.f, 0.f, 0.f};
    const bf16x8* B3 = (const bf16x8*)wotf;
#pragma unroll
    for (int kstep = 0; kstep < 8; kstep++) {
        bf16x8 a[4];
#pragma unroll
        for (int mt = 0; mt < 4; mt++) a[mt] = Hlbs[(kstep * 4 + mt) * 64 + lane];
#pragma unroll
        for (int nt = 0; nt < 2; nt++) {
            bf16x8 b = B3[((w * 2 + nt) * 8 + kstep) * 64 + lane];
#pragma unroll
            for (int mt = 0; mt < 4; mt++)
                acc3[mt][nt] = __builtin_amdgcn_mfma_f32_16x16x32_bf16(a[mt], b, acc3[mt][nt], 0, 0, 0);
        }
    }
#pragma unroll
    for (int mt = 0; mt < 4; mt++) {
#pragma unroll
        for (int r = 0; r < 4; r++) {
            int row = mt * 16 + q * 4 + r;
            if (row < rows) {
                int tok = toks_s[row];
                float wgt = wts_s[row];
                float* dst = out + (size_t)tok * DOUT;
#pragma unroll
                for (int nt = 0; nt < 2; nt++) {
                    int col = (w * 2 + nt) * 16 + mcol;
                    atomicAdd(&dst[col], wgt * acc3[mt][nt][r]);
                }
            }
        }
    }
}

extern "C" void kernel_launch(void* const* d_in, const int* in_sizes, int n_in,
                              void* d_out, int out_size, void* d_ws, size_t ws_size,
                              hipStream_t stream) {
    const float* x  = (const float*)d_in[0];
    const float* Wg = (const float*)d_in[1];
    const float* W1 = (const float*)d_in[2];
    const float* b1 = (const float*)d_in[3];
    const float* W2 = (const float*)d_in[4];
    const float* b2 = (const float*)d_in[5];
    const float* Wo = (const float*)d_in[6];
    const float* bo = (const float*)d_in[7];
    float* out = (float*)d_out;

    char* ws = (char*)d_ws;
    size_t off = 0;
    int* segcnt    = (int*)(ws + off);    off += 1024; // 8*32 ints
    int* list_tok  = (int*)(ws + off);    off += (size_t)NEXP * NSEG * SEGCAP * 4;
    float* list_w  = (float*)(ws + off);  off += (size_t)NEXP * NSEG * SEGCAP * 4;
    ushort_t* wt1f = (ushort_t*)(ws + off); off += (size_t)NEXP * DIN * HD * 2;
    ushort_t* wt2f = (ushort_t*)(ws + off); off += (size_t)NEXP * HD * HD * 2;
    ushort_t* wotf = (ushort_t*)(ws + off); off += (size_t)HD * DOUT * 2;

    pack_weights<<<400, 256, 0, stream>>>(W1, W2, Wo, wt1f, wt2f, wotf, segcnt);
    router_kernel<<<N_TOK / RT_TPB, 256, 0, stream>>>(x, Wg, segcnt, list_tok, list_w);
    init_out<<<(N_TOK * DOUT / 4) / 256, 256, 0, stream>>>(bo, out);
    expert_kernel<<<NEXP * NSEG * SEGTILES, 256, 0, stream>>>(x, segcnt, list_tok, list_w,
                                                              wt1f, wt2f, wotf, b1, b2, out);
}

// Round 6
// 213.273 us; speedup vs baseline: 1.1935x; 1.0025x over previous
//
#include <hip/hip_runtime.h>
#include <math.h>

typedef unsigned short ushort_t;
typedef __attribute__((ext_vector_type(8))) short bf16x8;
typedef __attribute__((ext_vector_type(4))) float f32x4;
typedef __attribute__((ext_vector_type(8))) unsigned short u16x8;

#define N_TOK 65536
#define DIN 128
#define HD 256
#define DOUT 128
#define NEXP 8
#define MT 32        /* tokens per tile: small tile -> 24.7KB LDS -> 6 blocks/CU */
#define NSEG 32      /* segments per expert */
#define SEGCAP 2048  /* worst case per segment */
#define SEGTILES (SEGCAP / MT) /* 64 */

#define G_INIT 8192             /* init_out part: N*DOUT/4/256 */
#define G_ROUTER 2048           /* router part: N_TOK/32 */
#define G_PACK 400              /* pack part */

__device__ __forceinline__ unsigned short f2bf(float f) {
    union { float f; unsigned int i; } v; v.f = f;
    unsigned int i = v.i;
    return (unsigned short)((i + 0x7FFFu + ((i >> 16) & 1u)) >> 16); // RNE
}

// ---------------------------------------------------------------------------
// prep kernel: three independent jobs fused into one dispatch (they share no
// data): [0,8192) init_out, [8192,10240) router, [10240,10640) pack_weights.
// segcnt is zeroed by a 1KB hipMemsetAsync BEFORE this dispatch (cross-block
// ordering inside one dispatch is undefined -> cannot zero here).
// ---------------------------------------------------------------------------
#define RT_TPB 32   /* tokens per 256-thread router block */
__global__ __launch_bounds__(256)
void prep_kernel(const float* __restrict__ x,
                 const float* __restrict__ Wg,
                 const float* __restrict__ W1,
                 const float* __restrict__ W2,
                 const float* __restrict__ Wo,
                 const float* __restrict__ bo,
                 int* __restrict__ segcnt,
                 int* __restrict__ list_tok,
                 float* __restrict__ list_w,
                 ushort_t* __restrict__ wt1f,
                 ushort_t* __restrict__ wt2f,
                 ushort_t* __restrict__ wotf,
                 float* __restrict__ out) {
    int tid = threadIdx.x;
    int bx = blockIdx.x;

    if (bx < G_INIT) {
        // ---- init_out: out[n][d] = bo[d] ----
        int gid = bx * 256 + tid;
        float4 b = ((const float4*)bo)[gid & 31];
        ((float4*)out)[gid] = b;
        return;
    }
    if (bx < G_INIT + G_ROUTER) {
        // ---- router: K-split, lane = token_local*8 + kslice ----
        int rb = bx - G_INIT;
        __shared__ float wgsT[NEXP * 132];
        __shared__ int lcnt[NEXP];
        __shared__ int lbase[NEXP];
        if (tid < NEXP) lcnt[tid] = 0;
        for (int i = tid; i < DIN * NEXP; i += 256) {
            int e = i & 7, k = i >> 3;   // Wg[k][e]
            wgsT[e * 132 + k] = Wg[i];
        }
        __syncthreads();

        int s = tid & 7;
        int tl = tid >> 3;
        int n = rb * RT_TPB + tl;

        const float4* xr = (const float4*)(x + (size_t)n * DIN + s * 16);
        float4 xv[4];
#pragma unroll
        for (int j = 0; j < 4; j++) xv[j] = xr[j];

        float lg[NEXP];
#pragma unroll
        for (int e = 0; e < NEXP; e++) {
            const float4* wp = (const float4*)(wgsT + e * 132 + s * 16);
            float a = 0.f;
#pragma unroll
            for (int j = 0; j < 4; j++) {
                float4 wv = wp[j];
                a += xv[j].x * wv.x + xv[j].y * wv.y + xv[j].z * wv.z + xv[j].w * wv.w;
            }
            lg[e] = a;
        }
#pragma unroll
        for (int d = 1; d < 8; d <<= 1) {
#pragma unroll
            for (int e = 0; e < NEXP; e++) lg[e] += __shfl_xor(lg[e], d, 64);
        }
        int e0 = 0; float v0 = lg[0];
#pragma unroll
        for (int e = 1; e < NEXP; e++) if (lg[e] > v0) { v0 = lg[e]; e0 = e; }
        int e1 = -1; float v1 = -3.0e38f;
#pragma unroll
        for (int e = 0; e < NEXP; e++) if (e != e0 && lg[e] > v1) { v1 = lg[e]; e1 = e; }
        float t = expf(v1 - v0);
        float inv = 1.0f / (1.0f + t);
        float w0 = inv, w1 = t * inv;

        bool writer = (s == 0);
        int p0 = 0, p1 = 0;
        if (writer) {
            p0 = atomicAdd(&lcnt[e0], 1);
            p1 = atomicAdd(&lcnt[e1], 1);
        }
        __syncthreads();
        int c = rb & (NSEG - 1);
        if (tid < NEXP) lbase[tid] = atomicAdd(&segcnt[tid * NSEG + c], lcnt[tid]);
        __syncthreads();
        if (writer) {
            int q0 = lbase[e0] + p0;
            int idx0 = (e0 * NSEG + c) * SEGCAP + q0;
            list_tok[idx0] = n;
            list_w[idx0] = w0;
            int q1 = lbase[e1] + p1;
            int idx1 = (e1 * NSEG + c) * SEGCAP + q1;
            list_tok[idx1] = n;
            list_w[idx1] = w1;
        }
        return;
    }
    // ---- pack_weights: fp32 -> bf16 MFMA B-frag order ----
    int id = (bx - G_INIT - G_ROUTER) * 256 + tid;
    const float* src; ushort_t* dst; int Nn, ksteps, c;
    if (id < 32768) {            // W1
        int e = id >> 12; c = id & 4095;
        Nn = HD; ksteps = 4; src = W1 + (size_t)e * DIN * HD; dst = wt1f + (size_t)id * 8;
    } else if (id < 98304) {     // W2
        int t2 = id - 32768; int e = t2 >> 13; c = t2 & 8191;
        Nn = HD; ksteps = 8; src = W2 + (size_t)e * HD * HD; dst = wt2f + (size_t)t2 * 8;
    } else {                     // Wo
        int t2 = id - 98304; c = t2;
        Nn = DOUT; ksteps = 8; src = Wo; dst = wotf + (size_t)t2 * 8;
    }
    int L = c & 63; int kc = c >> 6;
    int kstep = kc % ksteps; int ntile = kc / ksteps;
    int q = L >> 4, m = L & 15;
    int n = ntile * 16 + m; int k0 = kstep * 32 + q * 8;
    u16x8 v;
#pragma unroll
    for (int j = 0; j < 8; j++) v[j] = f2bf(src[(size_t)(k0 + j) * Nn + n]);
    *(u16x8*)dst = v;
}

// ---------------------------------------------------------------------------
// Fused per-expert MLP, 32-token tiles, 1m x 4n wave split (each wave reads
// the whole A tile from LDS and its N-quarter of B straight from L2-hot
// packed weights). LDS: bufA 8KB (x), bufH 16KB (h1 then h2 in place)
// -> 24.7KB, 6 blocks/CU = 24 waves/CU (2x round-5 occupancy; kernel was
// latency-bound with every pipe <18%).
// ---------------------------------------------------------------------------
__global__ __launch_bounds__(256, 6)
void expert_kernel(const float* __restrict__ x,
                   const int* __restrict__ segcnt,
                   const int* __restrict__ list_tok,
                   const float* __restrict__ list_w,
                   const ushort_t* __restrict__ wt1f,
                   const ushort_t* __restrict__ wt2f,
                   const ushort_t* __restrict__ wotf,
                   const float* __restrict__ b1,
                   const float* __restrict__ b2,
                   float* __restrict__ out) {
    int bid = blockIdx.x;
    int e = bid & 7;
    int c = (bid >> 3) & (NSEG - 1);
    int t = bid >> 8;            // 0..SEGTILES-1
    int cnt = segcnt[e * NSEG + c];
    int base = t * MT;
    if (base >= cnt) return;
    int rows = cnt - base; if (rows > MT) rows = MT;
    int lidx = (e * NSEG + c) * SEGCAP + base;

    __shared__ __align__(16) ushort_t bufA[4096];  // 8KB: x tile (32x128)
    __shared__ __align__(16) ushort_t bufH[8192];  // 16KB: h1, then h2 (32x256)
    __shared__ int toks_s[MT];
    __shared__ float wts_s[MT];

    int tid = threadIdx.x;
    int lane = tid & 63;
    int w = tid >> 6;
    int q = lane >> 4;
    int mcol = lane & 15;

    if (tid < MT) {
        int rr = tid < rows ? tid : rows - 1;
        toks_s[tid] = list_tok[lidx + rr];
        wts_s[tid] = list_w[lidx + rr];
    }
    // stage x tile (fp32 -> bf16) into A-frag layout (512 16B chunks)
    for (int cc = tid; cc < 512; cc += 256) {
        int row = cc >> 4;          // 0..31
        int kchunk = cc & 15;
        int rr = row < rows ? row : rows - 1;
        int tok = list_tok[lidx + rr];
        const float4* src = (const float4*)(x + (size_t)tok * DIN + kchunk * 8);
        float4 lo = src[0], hi = src[1];
        u16x8 v;
        v[0] = f2bf(lo.x); v[1] = f2bf(lo.y); v[2] = f2bf(lo.z); v[3] = f2bf(lo.w);
        v[4] = f2bf(hi.x); v[5] = f2bf(hi.y); v[6] = f2bf(hi.z); v[7] = f2bf(hi.w);
        int kstep = kchunk >> 2, qq = kchunk & 3;
        int dchunk = (kstep * 2 + (row >> 4)) * 64 + qq * 16 + (row & 15);
        ((u16x8*)bufA)[dchunk] = v;
    }
    __syncthreads();

    const bf16x8* Albs = (const bf16x8*)bufA;
    const bf16x8* Hlbs = (const bf16x8*)bufH;

    // ---- GEMM1: x[32x128] @ W1[128x256] -> h1 ----
    f32x4 acc[2][4];
#pragma unroll
    for (int mt = 0; mt < 2; mt++)
#pragma unroll
        for (int nt = 0; nt < 4; nt++) acc[mt][nt] = (f32x4){0.f, 0.f, 0.f, 0.f};
    const bf16x8* B1 = (const bf16x8*)(wt1f + (size_t)e * 4096 * 8);
#pragma unroll
    for (int kstep = 0; kstep < 4; kstep++) {
        bf16x8 a[2];
#pragma unroll
        for (int mt = 0; mt < 2; mt++) a[mt] = Albs[(kstep * 2 + mt) * 64 + lane];
#pragma unroll
        for (int nt = 0; nt < 4; nt++) {
            bf16x8 b = B1[((w * 4 + nt) * 4 + kstep) * 64 + lane];
#pragma unroll
            for (int mt = 0; mt < 2; mt++)
                acc[mt][nt] = __builtin_amdgcn_mfma_f32_16x16x32_bf16(a[mt], b, acc[mt][nt], 0, 0, 0);
        }
    }
    // epilogue 1: bias + relu -> bufH (h1) in A-frag layout
#pragma unroll
    for (int nt = 0; nt < 4; nt++) {
        int nn = (w * 4 + nt) * 16 + mcol;
        float bias = b1[e * HD + nn];
        int kstep = nn >> 5, qq = (nn >> 3) & 3, jj = nn & 7;
#pragma unroll
        for (int mt = 0; mt < 2; mt++) {
#pragma unroll
            for (int r = 0; r < 4; r++) {
                float v = acc[mt][nt][r] + bias;
                v = v > 0.f ? v : 0.f;
                int chunk = (kstep * 2 + mt) * 64 + qq * 16 + q * 4 + r;
                bufH[chunk * 8 + jj] = f2bf(v);
            }
        }
    }
    __syncthreads();

    // ---- GEMM2: h1[32x256] @ W2[256x256] -> h2 (regs) ----
    f32x4 acc2[2][4];
#pragma unroll
    for (int mt = 0; mt < 2; mt++)
#pragma unroll
        for (int nt = 0; nt < 4; nt++) acc2[mt][nt] = (f32x4){0.f, 0.f, 0.f, 0.f};
    const bf16x8* B2 = (const bf16x8*)(wt2f + (size_t)e * 8192 * 8);
#pragma unroll
    for (int kstep = 0; kstep < 8; kstep++) {
        bf16x8 a[2];
#pragma unroll
        for (int mt = 0; mt < 2; mt++) a[mt] = Hlbs[(kstep * 2 + mt) * 64 + lane];
#pragma unroll
        for (int nt = 0; nt < 4; nt++) {
            bf16x8 b = B2[((w * 4 + nt) * 8 + kstep) * 64 + lane];
#pragma unroll
            for (int mt = 0; mt < 2; mt++)
                acc2[mt][nt] = __builtin_amdgcn_mfma_f32_16x16x32_bf16(a[mt], b, acc2[mt][nt], 0, 0, 0);
        }
    }
    __syncthreads();  // all waves done READING h1 before overwrite
    // epilogue 2: bias + relu -> bufH (h2 over h1)
#pragma unroll
    for (int nt = 0; nt < 4; nt++) {
        int nn = (w * 4 + nt) * 16 + mcol;
        float bias = b2[e * HD + nn];
        int kstep = nn >> 5, qq = (nn >> 3) & 3, jj = nn & 7;
#pragma unroll
        for (int mt = 0; mt < 2; mt++) {
#pragma unroll
            for (int r = 0; r < 4; r++) {
                float v = acc2[mt][nt][r] + bias;
                v = v > 0.f ? v : 0.f;
                int chunk = (kstep * 2 + mt) * 64 + qq * 16 + q * 4 + r;
                bufH[chunk * 8 + jj] = f2bf(v);
            }
        }
    }
    __syncthreads();

    // ---- GEMM3: h2[32x256] @ Wo[256x128] -> y; weighted atomic combine ----
    f32x4 acc3[2][2];
#pragma unroll
    for (int mt = 0; mt < 2; mt++)
#pragma unroll
        for (int nt = 0; nt < 2; nt++) acc3[mt][nt] = (f32x4){0.f, 0.f, 0.f, 0.f};
    const bf16x8* B3 = (const bf16x8*)wotf;
#pragma unroll
    for (int kstep = 0; kstep < 8; kstep++) {
        bf16x8 a[2];
#pragma unroll
        for (int mt = 0; mt < 2; mt++) a[mt] = Hlbs[(kstep * 2 + mt) * 64 + lane];
#pragma unroll
        for (int nt = 0; nt < 2; nt++) {
            bf16x8 b = B3[((w * 2 + nt) * 8 + kstep) * 64 + lane];
#pragma unroll
            for (int mt = 0; mt < 2; mt++)
                acc3[mt][nt] = __builtin_amdgcn_mfma_f32_16x16x32_bf16(a[mt], b, acc3[mt][nt], 0, 0, 0);
        }
    }
#pragma unroll
    for (int mt = 0; mt < 2; mt++) {
#pragma unroll
        for (int r = 0; r < 4; r++) {
            int row = mt * 16 + q * 4 + r;
            if (row < rows) {
                int tok = toks_s[row];
                float wgt = wts_s[row];
                float* dst = out + (size_t)tok * DOUT;
#pragma unroll
                for (int nt = 0; nt < 2; nt++) {
                    int col = (w * 2 + nt) * 16 + mcol;
                    atomicAdd(&dst[col], wgt * acc3[mt][nt][r]);
                }
            }
        }
    }
}

extern "C" void kernel_launch(void* const* d_in, const int* in_sizes, int n_in,
                              void* d_out, int out_size, void* d_ws, size_t ws_size,
                              hipStream_t stream) {
    const float* x  = (const float*)d_in[0];
    const float* Wg = (const float*)d_in[1];
    const float* W1 = (const float*)d_in[2];
    const float* b1 = (const float*)d_in[3];
    const float* W2 = (const float*)d_in[4];
    const float* b2 = (const float*)d_in[5];
    const float* Wo = (const float*)d_in[6];
    const float* bo = (const float*)d_in[7];
    float* out = (float*)d_out;

    char* ws = (char*)d_ws;
    size_t off = 0;
    int* segcnt    = (int*)(ws + off);    off += 1024; // 8*32 ints
    int* list_tok  = (int*)(ws + off);    off += (size_t)NEXP * NSEG * SEGCAP * 4;
    float* list_w  = (float*)(ws + off);  off += (size_t)NEXP * NSEG * SEGCAP * 4;
    ushort_t* wt1f = (ushort_t*)(ws + off); off += (size_t)NEXP * DIN * HD * 2;
    ushort_t* wt2f = (ushort_t*)(ws + off); off += (size_t)NEXP * HD * HD * 2;
    ushort_t* wotf = (ushort_t*)(ws + off); off += (size_t)HD * DOUT * 2;

    hipMemsetAsync(segcnt, 0, 1024, stream);
    prep_kernel<<<G_INIT + G_ROUTER + G_PACK, 256, 0, stream>>>(
        x, Wg, W1, W2, Wo, bo, segcnt, list_tok, list_w, wt1f, wt2f, wotf, out);
    expert_kernel<<<NEXP * NSEG * SEGTILES, 256, 0, stream>>>(
        x, segcnt, list_tok, list_w, wt1f, wt2f, wotf, b1, b2, out);
}

// Round 7
// 208.076 us; speedup vs baseline: 1.2233x; 1.0250x over previous
//
#include <hip/hip_runtime.h>
#include <math.h>

typedef unsigned short ushort_t;
typedef __attribute__((ext_vector_type(8))) short bf16x8;
typedef __attribute__((ext_vector_type(4))) float f32x4;
typedef __attribute__((ext_vector_type(8))) unsigned short u16x8;

#define N_TOK 65536
#define DIN 128
#define HD 256
#define DOUT 128
#define NEXP 8
#define MT 64        /* tokens per tile (R3-proven) */
#define NSEG 32      /* segments per expert */
#define SEGCAP 2048  /* worst case per segment */
#define SEGTILES (SEGCAP / MT) /* 32 */

#define G_INIT 8192             /* init_out part: N*DOUT/4/256 */
#define G_ROUTER 2048           /* router part: N_TOK/32 */
#define G_PACK 400              /* pack part */

__device__ __forceinline__ unsigned short f2bf(float f) {
    union { float f; unsigned int i; } v; v.f = f;
    unsigned int i = v.i;
    return (unsigned short)((i + 0x7FFFu + ((i >> 16) & 1u)) >> 16); // RNE
}

// ---------------------------------------------------------------------------
// prep kernel: three independent jobs in one dispatch:
// [0,8192) init_out, [8192,10240) router, [10240,10640) pack_weights.
// segcnt is zeroed by a 1KB hipMemsetAsync BEFORE this dispatch.
// ---------------------------------------------------------------------------
#define RT_TPB 32   /* tokens per 256-thread router block */
__global__ __launch_bounds__(256)
void prep_kernel(const float* __restrict__ x,
                 const float* __restrict__ Wg,
                 const float* __restrict__ W1,
                 const float* __restrict__ W2,
                 const float* __restrict__ Wo,
                 const float* __restrict__ bo,
                 int* __restrict__ segcnt,
                 int* __restrict__ list_tok,
                 float* __restrict__ list_w,
                 ushort_t* __restrict__ wt1f,
                 ushort_t* __restrict__ wt2f,
                 ushort_t* __restrict__ wotf,
                 float* __restrict__ out) {
    int tid = threadIdx.x;
    int bx = blockIdx.x;

    if (bx < G_INIT) {
        int gid = bx * 256 + tid;
        float4 b = ((const float4*)bo)[gid & 31];
        ((float4*)out)[gid] = b;
        return;
    }
    if (bx < G_INIT + G_ROUTER) {
        int rb = bx - G_INIT;
        __shared__ float wgsT[NEXP * 132];
        __shared__ int lcnt[NEXP];
        __shared__ int lbase[NEXP];
        if (tid < NEXP) lcnt[tid] = 0;
        for (int i = tid; i < DIN * NEXP; i += 256) {
            int e = i & 7, k = i >> 3;   // Wg[k][e]
            wgsT[e * 132 + k] = Wg[i];
        }
        __syncthreads();

        int s = tid & 7;
        int tl = tid >> 3;
        int n = rb * RT_TPB + tl;

        const float4* xr = (const float4*)(x + (size_t)n * DIN + s * 16);
        float4 xv[4];
#pragma unroll
        for (int j = 0; j < 4; j++) xv[j] = xr[j];

        float lg[NEXP];
#pragma unroll
        for (int e = 0; e < NEXP; e++) {
            const float4* wp = (const float4*)(wgsT + e * 132 + s * 16);
            float a = 0.f;
#pragma unroll
            for (int j = 0; j < 4; j++) {
                float4 wv = wp[j];
                a += xv[j].x * wv.x + xv[j].y * wv.y + xv[j].z * wv.z + xv[j].w * wv.w;
            }
            lg[e] = a;
        }
#pragma unroll
        for (int d = 1; d < 8; d <<= 1) {
#pragma unroll
            for (int e = 0; e < NEXP; e++) lg[e] += __shfl_xor(lg[e], d, 64);
        }
        int e0 = 0; float v0 = lg[0];
#pragma unroll
        for (int e = 1; e < NEXP; e++) if (lg[e] > v0) { v0 = lg[e]; e0 = e; }
        int e1 = -1; float v1 = -3.0e38f;
#pragma unroll
        for (int e = 0; e < NEXP; e++) if (e != e0 && lg[e] > v1) { v1 = lg[e]; e1 = e; }
        float t = expf(v1 - v0);
        float inv = 1.0f / (1.0f + t);
        float w0 = inv, w1 = t * inv;

        bool writer = (s == 0);
        int p0 = 0, p1 = 0;
        if (writer) {
            p0 = atomicAdd(&lcnt[e0], 1);
            p1 = atomicAdd(&lcnt[e1], 1);
        }
        __syncthreads();
        int c = rb & (NSEG - 1);
        if (tid < NEXP) lbase[tid] = atomicAdd(&segcnt[tid * NSEG + c], lcnt[tid]);
        __syncthreads();
        if (writer) {
            int q0 = lbase[e0] + p0;
            int idx0 = (e0 * NSEG + c) * SEGCAP + q0;
            list_tok[idx0] = n;
            list_w[idx0] = w0;
            int q1 = lbase[e1] + p1;
            int idx1 = (e1 * NSEG + c) * SEGCAP + q1;
            list_tok[idx1] = n;
            list_w[idx1] = w1;
        }
        return;
    }
    // ---- pack_weights: fp32 -> bf16 MFMA B-frag order ----
    int id = (bx - G_INIT - G_ROUTER) * 256 + tid;
    const float* src; ushort_t* dst; int Nn, ksteps, c;
    if (id < 32768) {            // W1
        int e = id >> 12; c = id & 4095;
        Nn = HD; ksteps = 4; src = W1 + (size_t)e * DIN * HD; dst = wt1f + (size_t)id * 8;
    } else if (id < 98304) {     // W2
        int t2 = id - 32768; int e = t2 >> 13; c = t2 & 8191;
        Nn = HD; ksteps = 8; src = W2 + (size_t)e * HD * HD; dst = wt2f + (size_t)t2 * 8;
    } else {                     // Wo
        int t2 = id - 98304; c = t2;
        Nn = DOUT; ksteps = 8; src = Wo; dst = wotf + (size_t)t2 * 8;
    }
    int L = c & 63; int kc = c >> 6;
    int kstep = kc % ksteps; int ntile = kc / ksteps;
    int q = L >> 4, m = L & 15;
    int n = ntile * 16 + m; int k0 = kstep * 32 + q * 8;
    u16x8 v;
#pragma unroll
    for (int j = 0; j < 8; j++) v[j] = f2bf(src[(size_t)(k0 + j) * Nn + n]);
    *(u16x8*)dst = v;
}

// ---------------------------------------------------------------------------
// Fused per-expert MLP, 64-token tiles, 1m x 4n wave split, with explicit
// B-fragment software pipelining: initial b-frags of each GEMM are issued
// BEFORE the preceding __syncthreads (the barrier's vmcnt(0) drain guarantees
// arrival, overlapped with staging/epilogue); the kstep loop prefetches
// kstep+1 before MFMAing kstep. GEMM3's 16 frags issue right after GEMM2's
// MFMAs and land across the barrier + epilogue-2.
// LDS: bufA 16KB (x), bufH 32KB (h1 then h2 in place) -> 48.5KB, 3 blocks/CU.
// ---------------------------------------------------------------------------
__global__ __launch_bounds__(256, 3)
void expert_kernel(const float* __restrict__ x,
                   const int* __restrict__ segcnt,
                   const int* __restrict__ list_tok,
                   const float* __restrict__ list_w,
                   const ushort_t* __restrict__ wt1f,
                   const ushort_t* __restrict__ wt2f,
                   const ushort_t* __restrict__ wotf,
                   const float* __restrict__ b1,
                   const float* __restrict__ b2,
                   float* __restrict__ out) {
    int bid = blockIdx.x;
    int e = bid & 7;
    int c = (bid >> 3) & (NSEG - 1);
    int t = bid >> 8;            // 0..SEGTILES-1
    int cnt = segcnt[e * NSEG + c];
    int base = t * MT;
    if (base >= cnt) return;
    int rows = cnt - base; if (rows > MT) rows = MT;
    int lidx = (e * NSEG + c) * SEGCAP + base;

    __shared__ __align__(16) ushort_t bufA[8192];  // 16KB: x tile
    __shared__ __align__(16) ushort_t bufH[16384]; // 32KB: h1, then h2
    __shared__ int toks_s[MT];
    __shared__ float wts_s[MT];

    int tid = threadIdx.x;
    int lane = tid & 63;
    int w = tid >> 6;
    int q = lane >> 4;
    int mcol = lane & 15;

    const bf16x8* B1 = (const bf16x8*)(wt1f + (size_t)e * 4096 * 8);
    const bf16x8* B2 = (const bf16x8*)(wt2f + (size_t)e * 8192 * 8);
    const bf16x8* B3 = (const bf16x8*)wotf;

    // issue GEMM1's kstep-0 b-frags NOW: they land during staging + barrier
    bf16x8 b1c[4], b1n[4];
#pragma unroll
    for (int nt = 0; nt < 4; nt++) b1c[nt] = B1[((w * 4 + nt) * 4 + 0) * 64 + lane];

    if (tid < MT) {
        int rr = tid < rows ? tid : rows - 1;
        toks_s[tid] = list_tok[lidx + rr];
        wts_s[tid] = list_w[lidx + rr];
    }
    // stage x tile (fp32 -> bf16) into A-frag layout (1024 16B chunks)
    for (int cc = tid; cc < 1024; cc += 256) {
        int row = cc >> 4;
        int kchunk = cc & 15;
        int rr = row < rows ? row : rows - 1;
        int tok = list_tok[lidx + rr];
        const float4* src = (const float4*)(x + (size_t)tok * DIN + kchunk * 8);
        float4 lo = src[0], hi = src[1];
        u16x8 v;
        v[0] = f2bf(lo.x); v[1] = f2bf(lo.y); v[2] = f2bf(lo.z); v[3] = f2bf(lo.w);
        v[4] = f2bf(hi.x); v[5] = f2bf(hi.y); v[6] = f2bf(hi.z); v[7] = f2bf(hi.w);
        int kstep = kchunk >> 2, qq = kchunk & 3;
        int dchunk = (kstep * 4 + (row >> 4)) * 64 + qq * 16 + (row & 15);
        ((u16x8*)bufA)[dchunk] = v;
    }
    __syncthreads();

    const bf16x8* Albs = (const bf16x8*)bufA;
    const bf16x8* Hlbs = (const bf16x8*)bufH;

    // ---- GEMM1: x[64x128] @ W1[128x256] -> h1 (depth-1 B pipeline) ----
    f32x4 acc[4][4];
#pragma unroll
    for (int mt = 0; mt < 4; mt++)
#pragma unroll
        for (int nt = 0; nt < 4; nt++) acc[mt][nt] = (f32x4){0.f, 0.f, 0.f, 0.f};
#pragma unroll
    for (int kstep = 0; kstep < 4; kstep++) {
        if (kstep < 3) {
#pragma unroll
            for (int nt = 0; nt < 4; nt++)
                b1n[nt] = B1[((w * 4 + nt) * 4 + kstep + 1) * 64 + lane];
        }
        bf16x8 a[4];
#pragma unroll
        for (int mt = 0; mt < 4; mt++) a[mt] = Albs[(kstep * 4 + mt) * 64 + lane];
#pragma unroll
        for (int nt = 0; nt < 4; nt++)
#pragma unroll
            for (int mt = 0; mt < 4; mt++)
                acc[mt][nt] = __builtin_amdgcn_mfma_f32_16x16x32_bf16(a[mt], b1c[nt], acc[mt][nt], 0, 0, 0);
#pragma unroll
        for (int nt = 0; nt < 4; nt++) b1c[nt] = b1n[nt];
    }
    // epilogue 1: bias + relu -> bufH (h1) in A-frag layout
#pragma unroll
    for (int nt = 0; nt < 4; nt++) {
        int nn = (w * 4 + nt) * 16 + mcol;
        float bias = b1[e * HD + nn];
        int kstep = nn >> 5, qq = (nn >> 3) & 3, jj = nn & 7;
#pragma unroll
        for (int mt = 0; mt < 4; mt++) {
#pragma unroll
            for (int r = 0; r < 4; r++) {
                float v = acc[mt][nt][r] + bias;
                v = v > 0.f ? v : 0.f;
                int chunk = (kstep * 4 + mt) * 64 + qq * 16 + q * 4 + r;
                bufH[chunk * 8 + jj] = f2bf(v);
            }
        }
    }
    // issue GEMM2's kstep-0 b-frags: land during the barrier
    bf16x8 b2c[4], b2n[4];
#pragma unroll
    for (int nt = 0; nt < 4; nt++) b2c[nt] = B2[((w * 4 + nt) * 8 + 0) * 64 + lane];
    __syncthreads();

    // ---- GEMM2: h1[64x256] @ W2[256x256] -> h2 (regs; depth-1 B pipeline) ----
    f32x4 acc2[4][4];
#pragma unroll
    for (int mt = 0; mt < 4; mt++)
#pragma unroll
        for (int nt = 0; nt < 4; nt++) acc2[mt][nt] = (f32x4){0.f, 0.f, 0.f, 0.f};
#pragma unroll
    for (int kstep = 0; kstep < 8; kstep++) {
        if (kstep < 7) {
#pragma unroll
            for (int nt = 0; nt < 4; nt++)
                b2n[nt] = B2[((w * 4 + nt) * 8 + kstep + 1) * 64 + lane];
        }
        bf16x8 a[4];
#pragma unroll
        for (int mt = 0; mt < 4; mt++) a[mt] = Hlbs[(kstep * 4 + mt) * 64 + lane];
#pragma unroll
        for (int nt = 0; nt < 4; nt++)
#pragma unroll
            for (int mt = 0; mt < 4; mt++)
                acc2[mt][nt] = __builtin_amdgcn_mfma_f32_16x16x32_bf16(a[mt], b2c[nt], acc2[mt][nt], 0, 0, 0);
#pragma unroll
        for (int nt = 0; nt < 4; nt++) b2c[nt] = b2n[nt];
    }
    // issue ALL of GEMM3's 16 b-frags: land across barrier + epilogue-2
    bf16x8 b3f[16];
#pragma unroll
    for (int kstep = 0; kstep < 8; kstep++)
#pragma unroll
        for (int nt = 0; nt < 2; nt++)
            b3f[kstep * 2 + nt] = B3[((w * 2 + nt) * 8 + kstep) * 64 + lane];
    __syncthreads();  // all waves done READING h1 before overwrite
    // epilogue 2: bias + relu -> bufH (h2 over h1)
#pragma unroll
    for (int nt = 0; nt < 4; nt++) {
        int nn = (w * 4 + nt) * 16 + mcol;
        float bias = b2[e * HD + nn];
        int kstep = nn >> 5, qq = (nn >> 3) & 3, jj = nn & 7;
#pragma unroll
        for (int mt = 0; mt < 4; mt++) {
#pragma unroll
            for (int r = 0; r < 4; r++) {
                float v = acc2[mt][nt][r] + bias;
                v = v > 0.f ? v : 0.f;
                int chunk = (kstep * 4 + mt) * 64 + qq * 16 + q * 4 + r;
                bufH[chunk * 8 + jj] = f2bf(v);
            }
        }
    }
    __syncthreads();

    // ---- GEMM3: h2[64x256] @ Wo[256x128] -> y; weighted atomic combine ----
    f32x4 acc3[4][2];
#pragma unroll
    for (int mt = 0; mt < 4; mt++)
#pragma unroll
        for (int nt = 0; nt < 2; nt++) acc3[mt][nt] = (f32x4){0.f, 0.f, 0.f, 0.f};
#pragma unroll
    for (int kstep = 0; kstep < 8; kstep++) {
        bf16x8 a[4];
#pragma unroll
        for (int mt = 0; mt < 4; mt++) a[mt] = Hlbs[(kstep * 4 + mt) * 64 + lane];
#pragma unroll
        for (int nt = 0; nt < 2; nt++)
#pragma unroll
            for (int mt = 0; mt < 4; mt++)
                acc3[mt][nt] = __builtin_amdgcn_mfma_f32_16x16x32_bf16(a[mt], b3f[kstep * 2 + nt], acc3[mt][nt], 0, 0, 0);
    }
#pragma unroll
    for (int mt = 0; mt < 4; mt++) {
#pragma unroll
        for (int r = 0; r < 4; r++) {
            int row = mt * 16 + q * 4 + r;
            if (row < rows) {
                int tok = toks_s[row];
                float wgt = wts_s[row];
                float* dst = out + (size_t)tok * DOUT;
#pragma unroll
                for (int nt = 0; nt < 2; nt++) {
                    int col = (w * 2 + nt) * 16 + mcol;
                    atomicAdd(&dst[col], wgt * acc3[mt][nt][r]);
                }
            }
        }
    }
}

extern "C" void kernel_launch(void* const* d_in, const int* in_sizes, int n_in,
                              void* d_out, int out_size, void* d_ws, size_t ws_size,
                              hipStream_t stream) {
    const float* x  = (const float*)d_in[0];
    const float* Wg = (const float*)d_in[1];
    const float* W1 = (const float*)d_in[2];
    const float* b1 = (const float*)d_in[3];
    const float* W2 = (const float*)d_in[4];
    const float* b2 = (const float*)d_in[5];
    const float* Wo = (const float*)d_in[6];
    const float* bo = (const float*)d_in[7];
    float* out = (float*)d_out;

    char* ws = (char*)d_ws;
    size_t off = 0;
    int* segcnt    = (int*)(ws + off);    off += 1024; // 8*32 ints
    int* list_tok  = (int*)(ws + off);    off += (size_t)NEXP * NSEG * SEGCAP * 4;
    float* list_w  = (float*)(ws + off);  off += (size_t)NEXP * NSEG * SEGCAP * 4;
    ushort_t* wt1f = (ushort_t*)(ws + off); off += (size_t)NEXP * DIN * HD * 2;
    ushort_t* wt2f = (ushort_t*)(ws + off); off += (size_t)NEXP * HD * HD * 2;
    ushort_t* wotf = (ushort_t*)(ws + off); off += (size_t)HD * DOUT * 2;

    hipMemsetAsync(segcnt, 0, 1024, stream);
    prep_kernel<<<G_INIT + G_ROUTER + G_PACK, 256, 0, stream>>>(
        x, Wg, W1, W2, Wo, bo, segcnt, list_tok, list_w, wt1f, wt2f, wotf, out);
    expert_kernel<<<NEXP * NSEG * SEGTILES, 256, 0, stream>>>(
        x, segcnt, list_tok, list_w, wt1f, wt2f, wotf, b1, b2, out);
}